// Round 12
// baseline (183.849 us; speedup 1.0000x reference)
//
#include <hip/hip_runtime.h>
#include <hip/hip_bf16.h>

#define N_N 128
#define N_C 7
#define N_H 96
#define N_W 192
#define HW (N_H * N_W)            // 18432
#define CHW (N_C * HW)            // 129024
#define NHW (N_N * HW)            // 2359296
#define NPTS 100
#define NK (N_N * N_C)            // 896
#define NK2 (NK / 2)              // 448 float2 per row
#define NK4 (NK / 4)              // 224 float4 per row
#define NV (NHW / 4)              // 589824 float4 per tensor (channel 0)
#define HV (HW / 4)               // 4608
#define CV (CHW / 4)              // 32256
#define SIGMA_F 2.0f

#define BG_BLOCKS 1024
#define TILE 4
#define NTILE (NPTS / TILE)       // 25
#define PAIRT (NTILE * (NTILE + 1) / 2)   // 325 tiles with ti<=tj

#define RL __ATOMIC_RELEASE
#define SCOPE __HIP_MEMORY_SCOPE_AGENT

// ======================= PROBE KERNELS (instrumentation) ====================
// Same work as the real kernels, repeated `iters` times. `dummy`==0 at runtime
// (compiler can't prove it) so every iteration re-issues all global loads.
// All writes are idempotent; real kernels run afterwards and overwrite.

__global__ __launch_bounds__(256) void fusedA_probe(
        const float* __restrict__ in, const float* __restrict__ tg,
        const int* __restrict__ px, const int* __restrict__ py,
        double* __restrict__ bgpart, float* __restrict__ Pt,
        float* __restrict__ Gt, float* __restrict__ term1,
        unsigned long long* __restrict__ fpr, int* __restrict__ doneCnt,
        int iters, int dummy) {
    __shared__ float swf[4];
    __shared__ unsigned long long swh[4];
    const int b = blockIdx.x;
    const int t = threadIdx.x;
    const int w = t >> 6;
    const int lane = t & 63;

    if (b >= BG_BLOCKS + 2 * NPTS) {
        if (t == 0) *doneCnt = 0;
        return;
    }

#pragma unroll 1
    for (int iter = 0; iter < iters; ++iter) {
        const float* inp = in + (size_t)iter * dummy;
        const float* tgp = tg + (size_t)iter * dummy;
        if (b < BG_BLOCKS) {
            const float4* in4 = (const float4*)inp;
            const float4* tg4 = (const float4*)tgp;
            float s = 0.0f;
            for (int e = b * 256 + t; e < NV; e += BG_BLOCKS * 256) {
                int n = e / HV;
                int r = e - n * HV;
                float4 x4 = in4[n * CV + r];
                float4 t4 = tg4[n * CV + r];
                const float* xp = &x4.x;
                const float* tp = &t4.x;
#pragma unroll
                for (int q = 0; q < 4; ++q) {
                    float x = xp[q], tt = tp[q];
                    float u = __expf(-fabsf(x));
                    s += fmaxf(x, 0.0f) - x * tt + __logf(1.0f + u);
                }
            }
#pragma unroll
            for (int m = 32; m >= 1; m >>= 1) s += __shfl_xor(s, m);
            if (lane == 0) swf[w] = s;
            __syncthreads();
            if (t == 0) bgpart[b] = (double)(swf[0] + swf[1] + swf[2] + swf[3]);
            __syncthreads();
        } else if (b < BG_BLOCKS + NPTS) {
            const int i = b - BG_BLOCKS;
            const int base = py[i] * N_W + px[i];
            float s = 0.0f;
            for (int k = t; k < NK; k += 256) {
                int n = k / N_C;
                int c = k - n * N_C;
                float p = inp[n * CHW + c * HW + base];
                Pt[i * NK + k] = p;
                s += (p > 0.0f) ? p * __logf(p) : 0.0f;
            }
#pragma unroll
            for (int m = 32; m >= 1; m >>= 1) s += __shfl_xor(s, m);
            if (lane == 0) swf[w] = s;
            __syncthreads();
            if (t == 0) term1[i] = swf[0] + swf[1] + swf[2] + swf[3];
            __syncthreads();
        } else {
            const int i = b - BG_BLOCKS - NPTS;
            const int base = py[i] * N_W + px[i];
            unsigned long long h = 0ull;
            for (int k = t; k < NK; k += 256) {
                int n = k / N_C;
                int c = k - n * N_C;
                float g = tgp[n * CHW + c * HW + base];
                Gt[i * NK + k] = g;
                unsigned long long m = (unsigned long long)__float_as_uint(g)
                                     ^ (0x9E3779B97F4A7C15ULL * (unsigned long long)(k + 1));
                m *= 0xC2B2AE3D27D4EB4FULL;
                h ^= m ^ (m >> 31);
            }
#pragma unroll
            for (int m = 32; m >= 1; m >>= 1)
                h ^= (unsigned long long)__shfl_xor((long long)h, m);
            if (lane == 0) swh[w] = h;
            __syncthreads();
            if (t == 0) fpr[i] = swh[0] ^ swh[1] ^ swh[2] ^ swh[3];
            __syncthreads();
        }
    }
}

__global__ __launch_bounds__(256) void pairs_probe(
        const float* __restrict__ Pt, const float* __restrict__ Gt,
        const float* __restrict__ term1,
        const int* __restrict__ px, const int* __restrict__ py,
        const unsigned long long* __restrict__ fpr,
        double* __restrict__ klpart, int* __restrict__ cntpart,
        int iters, int dummy) {
    __shared__ __align__(16) float sPI[TILE * NK];
    __shared__ __align__(16) float sPJ[TILE * NK];
    __shared__ float sT1[8];
    __shared__ unsigned long long sFp[8];
    __shared__ int sPx[8], sPy[8];
    __shared__ double skl[4];
    __shared__ int scnt4[4];

    const int bidx = blockIdx.x;
    const int t = threadIdx.x;
    const int w = t >> 6;
    const int lane = t & 63;

    int ti = 0, rem = bidx;
    while (rem >= NTILE - ti) { rem -= NTILE - ti; ++ti; }
    const int tj = ti + rem;

#pragma unroll 1
    for (int iter = 0; iter < iters; ++iter) {
        const float* Ptp = Pt + (size_t)iter * dummy;
        if (t < 8) {
            int g = (t < 4) ? (ti * TILE + t) : (tj * TILE + (t - 4));
            sT1[t] = term1[g];
            sFp[t] = fpr[g];
            sPx[t] = px[g];
            sPy[t] = py[g];
        }
        {
            const float4* Pt4 = (const float4*)Ptp;
            float4* sI4 = (float4*)sPI;
            float4* sJ4 = (float4*)sPJ;
            for (int idx = t; idx < TILE * NK4; idx += 256) {
                int r = idx / NK4, q = idx - r * NK4;
                sI4[idx] = Pt4[(ti * TILE + r) * NK4 + q];
                sJ4[idx] = Pt4[(tj * TILE + r) * NK4 + q];
            }
        }
        __syncthreads();

        const float2* sPI2 = (const float2*)sPI;
        const int I = ti * TILE + w;
        float2 piv[7];
#pragma unroll
        for (int it = 0; it < 7; ++it) piv[it] = sPI2[w * NK2 + lane + it * 64];

        double kl = 0.0;
        int cnt = 0;
#pragma unroll
        for (int bb = 0; bb < TILE; ++bb) {
            const int J = tj * TILE + bb;
            const float2* pj2 = (const float2*)(sPJ + bb * NK);
            float cross = 0.0f;
#pragma unroll
            for (int it = 0; it < 7; ++it) {
                float2 pj = pj2[lane + it * 64];
                cross = fmaf(piv[it].x, pj.x, cross);
                cross = fmaf(piv[it].y, pj.y, cross);
            }
#pragma unroll
            for (int m = 32; m >= 1; m >>= 1) cross += __shfl_xor(cross, m);

            bool eqv;
            if (I == J) {
                eqv = true;
            } else if (sFp[w] != sFp[4 + bb]) {
                eqv = false;
            } else {
                const float2* gi = (const float2*)(Gt + I * NK);
                const float2* gj = (const float2*)(Gt + J * NK);
                int ef = 1;
#pragma unroll
                for (int it = 0; it < 7; ++it) {
                    int q = lane + it * 64;
                    float2 a = gi[q], c2 = gj[q];
                    ef &= (a.x == c2.x) & (a.y == c2.y);
                }
                eqv = __all(ef);
            }
            if (lane == 0) {
                float Dij = (sT1[4 + bb] - cross) * (1.0f / (float)N_N);
                float Dji = (sT1[w] - cross) * (1.0f / (float)N_N);
                float L = eqv ? (Dij + Dji)
                              : (float)(N_N * N_C) *
                                (fmaxf(SIGMA_F - Dij, 0.0f) + fmaxf(SIGMA_F - Dji, 0.0f));
                bool mask = (I < J) && (sPx[w] != sPx[4 + bb]) && (sPy[w] != sPy[4 + bb]);
                if (mask) { kl += (double)L; cnt += 1; }
            }
        }

        if (lane == 0) { skl[w] = kl; scnt4[w] = cnt; }
        __syncthreads();
        if (t == 0) {
            klpart[bidx] = skl[0] + skl[1] + skl[2] + skl[3];
            cntpart[bidx] = scnt4[0] + scnt4[1] + scnt4[2] + scnt4[3];
        }
        __syncthreads();
    }
}

// ======================= REAL KERNELS (R11, unchanged) ======================
__global__ __launch_bounds__(256) void fusedA_kernel(
        const float* __restrict__ in, const float* __restrict__ tg,
        const int* __restrict__ px, const int* __restrict__ py,
        double* __restrict__ bgpart, float* __restrict__ Pt,
        float* __restrict__ Gt, float* __restrict__ term1,
        unsigned long long* __restrict__ fpr, int* __restrict__ doneCnt) {
    __shared__ float swf[4];
    __shared__ unsigned long long swh[4];
    const int b = blockIdx.x;
    const int t = threadIdx.x;
    const int w = t >> 6;
    const int lane = t & 63;

    if (b >= BG_BLOCKS + 2 * NPTS) {
        if (t == 0) *doneCnt = 0;
        return;
    }

    if (b < BG_BLOCKS) {
        const float4* in4 = (const float4*)in;
        const float4* tg4 = (const float4*)tg;
        float s = 0.0f;
        for (int e = b * 256 + t; e < NV; e += BG_BLOCKS * 256) {
            int n = e / HV;
            int r = e - n * HV;
            float4 x4 = in4[n * CV + r];
            float4 t4 = tg4[n * CV + r];
            const float* xp = &x4.x;
            const float* tp = &t4.x;
#pragma unroll
            for (int q = 0; q < 4; ++q) {
                float x = xp[q], tt = tp[q];
                float u = __expf(-fabsf(x));
                s += fmaxf(x, 0.0f) - x * tt + __logf(1.0f + u);
            }
        }
#pragma unroll
        for (int m = 32; m >= 1; m >>= 1) s += __shfl_xor(s, m);
        if (lane == 0) swf[w] = s;
        __syncthreads();
        if (t == 0) bgpart[b] = (double)(swf[0] + swf[1] + swf[2] + swf[3]);
    } else if (b < BG_BLOCKS + NPTS) {
        const int i = b - BG_BLOCKS;
        const int base = py[i] * N_W + px[i];
        float s = 0.0f;
        for (int k = t; k < NK; k += 256) {
            int n = k / N_C;
            int c = k - n * N_C;
            float p = in[n * CHW + c * HW + base];
            Pt[i * NK + k] = p;
            s += (p > 0.0f) ? p * __logf(p) : 0.0f;
        }
#pragma unroll
        for (int m = 32; m >= 1; m >>= 1) s += __shfl_xor(s, m);
        if (lane == 0) swf[w] = s;
        __syncthreads();
        if (t == 0) term1[i] = swf[0] + swf[1] + swf[2] + swf[3];
    } else {
        const int i = b - BG_BLOCKS - NPTS;
        const int base = py[i] * N_W + px[i];
        unsigned long long h = 0ull;
        for (int k = t; k < NK; k += 256) {
            int n = k / N_C;
            int c = k - n * N_C;
            float g = tg[n * CHW + c * HW + base];
            Gt[i * NK + k] = g;
            unsigned long long m = (unsigned long long)__float_as_uint(g)
                                 ^ (0x9E3779B97F4A7C15ULL * (unsigned long long)(k + 1));
            m *= 0xC2B2AE3D27D4EB4FULL;
            h ^= m ^ (m >> 31);
        }
#pragma unroll
        for (int m = 32; m >= 1; m >>= 1)
            h ^= (unsigned long long)__shfl_xor((long long)h, m);
        if (lane == 0) swh[w] = h;
        __syncthreads();
        if (t == 0) fpr[i] = swh[0] ^ swh[1] ^ swh[2] ^ swh[3];
    }
}

__global__ __launch_bounds__(256) void pairsfin_kernel(
        const float* __restrict__ Pt, const float* __restrict__ Gt,
        const float* __restrict__ term1,
        const int* __restrict__ px, const int* __restrict__ py,
        const unsigned long long* __restrict__ fpr,
        const double* __restrict__ bgpart,
        double* __restrict__ klpart, int* __restrict__ cntpart,
        int* __restrict__ doneCnt, float* __restrict__ out) {
    __shared__ __align__(16) float sPI[TILE * NK];
    __shared__ __align__(16) float sPJ[TILE * NK];
    __shared__ float sT1[8];
    __shared__ unsigned long long sFp[8];
    __shared__ int sPx[8], sPy[8];
    __shared__ double skl[4];
    __shared__ int scnt4[4];
    __shared__ int slast;
    __shared__ double sred[256];
    __shared__ int sicnt[256];

    const int bidx = blockIdx.x;
    const int t = threadIdx.x;
    const int w = t >> 6;
    const int lane = t & 63;

    int ti = 0, rem = bidx;
    while (rem >= NTILE - ti) { rem -= NTILE - ti; ++ti; }
    const int tj = ti + rem;

    if (t < 8) {
        int g = (t < 4) ? (ti * TILE + t) : (tj * TILE + (t - 4));
        sT1[t] = term1[g];
        sFp[t] = fpr[g];
        sPx[t] = px[g];
        sPy[t] = py[g];
    }
    {
        const float4* Pt4 = (const float4*)Pt;
        float4* sI4 = (float4*)sPI;
        float4* sJ4 = (float4*)sPJ;
        for (int idx = t; idx < TILE * NK4; idx += 256) {
            int r = idx / NK4, q = idx - r * NK4;
            sI4[idx] = Pt4[(ti * TILE + r) * NK4 + q];
            sJ4[idx] = Pt4[(tj * TILE + r) * NK4 + q];
        }
    }
    __syncthreads();

    const float2* sPI2 = (const float2*)sPI;
    const int I = ti * TILE + w;
    float2 piv[7];
#pragma unroll
    for (int it = 0; it < 7; ++it) piv[it] = sPI2[w * NK2 + lane + it * 64];

    double kl = 0.0;
    int cnt = 0;
#pragma unroll
    for (int bb = 0; bb < TILE; ++bb) {
        const int J = tj * TILE + bb;
        const float2* pj2 = (const float2*)(sPJ + bb * NK);
        float cross = 0.0f;
#pragma unroll
        for (int it = 0; it < 7; ++it) {
            float2 pj = pj2[lane + it * 64];
            cross = fmaf(piv[it].x, pj.x, cross);
            cross = fmaf(piv[it].y, pj.y, cross);
        }
#pragma unroll
        for (int m = 32; m >= 1; m >>= 1) cross += __shfl_xor(cross, m);

        bool eqv;
        if (I == J) {
            eqv = true;
        } else if (sFp[w] != sFp[4 + bb]) {
            eqv = false;
        } else {
            const float2* gi = (const float2*)(Gt + I * NK);
            const float2* gj = (const float2*)(Gt + J * NK);
            int ef = 1;
#pragma unroll
            for (int it = 0; it < 7; ++it) {
                int q = lane + it * 64;
                float2 a = gi[q], c2 = gj[q];
                ef &= (a.x == c2.x) & (a.y == c2.y);
            }
            eqv = __all(ef);
        }
        if (lane == 0) {
            float Dij = (sT1[4 + bb] - cross) * (1.0f / (float)N_N);
            float Dji = (sT1[w] - cross) * (1.0f / (float)N_N);
            float L = eqv ? (Dij + Dji)
                          : (float)(N_N * N_C) *
                            (fmaxf(SIGMA_F - Dij, 0.0f) + fmaxf(SIGMA_F - Dji, 0.0f));
            bool mask = (I < J) && (sPx[w] != sPx[4 + bb]) && (sPy[w] != sPy[4 + bb]);
            if (mask) { kl += (double)L; cnt += 1; }
        }
    }

    if (lane == 0) { skl[w] = kl; scnt4[w] = cnt; }
    __syncthreads();
    if (t == 0) {
        klpart[bidx] = skl[0] + skl[1] + skl[2] + skl[3];
        cntpart[bidx] = scnt4[0] + scnt4[1] + scnt4[2] + scnt4[3];
        int old = __hip_atomic_fetch_add(doneCnt, 1, RL, SCOPE);
        slast = (old == PAIRT - 1) ? 1 : 0;
    }
    __syncthreads();

    if (slast) {
        __builtin_amdgcn_fence(__ATOMIC_ACQUIRE, "agent");
        double s = 0.0;
        for (int q = t; q < BG_BLOCKS; q += 256) s += bgpart[q];
        double kq = 0.0;
        int cq = 0;
        for (int q = t; q < PAIRT; q += 256) { kq += klpart[q]; cq += cntpart[q]; }
        sred[t] = s;
        __syncthreads();
        for (int off = 128; off > 0; off >>= 1) {
            if (t < off) sred[t] += sred[t + off];
            __syncthreads();
        }
        double bg_sum = sred[0];
        __syncthreads();
        sred[t] = kq;
        sicnt[t] = cq;
        __syncthreads();
        for (int off = 128; off > 0; off >>= 1) {
            if (t < off) { sred[t] += sred[t + off]; sicnt[t] += sicnt[t + off]; }
            __syncthreads();
        }
        if (t == 0)
            out[0] = (float)(bg_sum / (double)NHW + sred[0] / (double)sicnt[0]);
    }
}

// ---------------- launch ---------------------------------------------------
extern "C" void kernel_launch(void* const* d_in, const int* in_sizes, int n_in,
                              void* d_out, int out_size, void* d_ws, size_t ws_size,
                              hipStream_t stream) {
    const float* inputs  = (const float*)d_in[0];
    const float* targets = (const float*)d_in[1];
    const int*   px      = (const int*)d_in[2];
    const int*   py      = (const int*)d_in[3];
    float* out = (float*)d_out;

    char* ws = (char*)d_ws;
    int*    doneCnt = (int*)ws;
    double* bgpart  = (double*)(ws + 256);
    double* klpart  = (double*)(ws + 8448);
    int*    cntpart = (int*)(ws + 18688);
    float*  term1   = (float*)(ws + 24064);
    unsigned long long* fpr = (unsigned long long*)(ws + 24576);
    float*  Pt      = (float*)(ws + 25600);
    float*  Gt      = (float*)(ws + 384000);

    // ---- probes (idempotent; real kernels overwrite afterwards) ----
    fusedA_probe<<<BG_BLOCKS + 2 * NPTS + 1, 256, 0, stream>>>(
        inputs, targets, px, py, bgpart, Pt, Gt, term1, fpr, doneCnt, 16, 0);
    pairs_probe<<<PAIRT, 256, 0, stream>>>(
        Pt, Gt, term1, px, py, fpr, klpart, cntpart, 32, 0);

    // ---- real path (R11) ----
    fusedA_kernel<<<BG_BLOCKS + 2 * NPTS + 1, 256, 0, stream>>>(
        inputs, targets, px, py, bgpart, Pt, Gt, term1, fpr, doneCnt);
    pairsfin_kernel<<<PAIRT, 256, 0, stream>>>(
        Pt, Gt, term1, px, py, fpr, bgpart, klpart, cntpart, doneCnt, out);
}

// Round 13
// 51.100 us; speedup vs baseline: 3.5978x; 3.5978x over previous
//
#include <hip/hip_runtime.h>
#include <hip/hip_bf16.h>

#define N_N 128
#define N_C 7
#define N_H 96
#define N_W 192
#define HW (N_H * N_W)            // 18432
#define CHW (N_C * HW)            // 129024
#define NHW (N_N * HW)            // 2359296
#define NPTS 100
#define NK (N_N * N_C)            // 896
#define NK2 (NK / 2)              // 448 float2 per row
#define NK4 (NK / 4)              // 224 float4 per row
#define NV (NHW / 4)              // 589824 float4 per tensor (channel 0)
#define HV (HW / 4)               // 4608
#define CV (CHW / 4)              // 32256
#define SIGMA_F 2.0f

#define TILE 4
#define NTILE (NPTS / TILE)       // 25
#define NDIAG NTILE               // 25 diagonal tiles (gather + own pairs)
#define NOFF (NTILE * (NTILE - 1) / 2)   // 300 off-diagonal tiles
#define PAIRB (NDIAG + NOFF)      // 325
#define BGB 256                   // bg blocks
#define GRID (PAIRB + BGB)        // 581 blocks, all co-resident

#define AQ __ATOMIC_ACQUIRE
#define RL __ATOMIC_RELEASE
#define RX __ATOMIC_RELAXED
#define SCOPE __HIP_MEMORY_SCOPE_AGENT

// ======================= single mono kernel =================================
// blocks [0,25)    : diagonal tile ti: gather group ti's 4 rows (P+G) ->
//                    Pt/Gt/term1/fpr, publish rowDone[ti] (own cache line),
//                    then compute its within-group pairs.
// blocks [25,325)  : off-diag tile (ti,tj): poll rowDone[ti], rowDone[tj]
//                    (<=24 pollers/line, s_sleep(16)), stage P rows, pairs.
// blocks [325,581) : bg BCE sweep -> bgpart, bgDone.
// Last pair block (pairDone==324) waits for bgDone==256 (single poller),
// acquire-fences, reduces everything, writes out.
__global__ __launch_bounds__(256) void mono_kernel(
        const float* __restrict__ in, const float* __restrict__ tg,
        const int* __restrict__ px, const int* __restrict__ py,
        int* rowDone,                       // 25 ints at 64B stride
        int* bgDone, int* pairDone,         // separate cache lines
        double* bgpart,                     // [256]
        double* klpart,                     // [325]
        int* cntpart,                       // [325]
        float* term1,                       // [100]
        unsigned long long* fpr,            // [100]
        float* Pt, float* Gt,               // [100][896]
        float* out) {
    __shared__ __align__(16) float sPI[TILE * NK];   // 14336 B
    __shared__ __align__(16) float sPJ[TILE * NK];   // 14336 B
    __shared__ float swf[4];
    __shared__ unsigned long long swh[4];
    __shared__ float sT1[8];
    __shared__ unsigned long long sFp[8];
    __shared__ int sPx[8], sPy[8];
    __shared__ double skl[4];
    __shared__ int scnt4[4];
    __shared__ int slast;
    __shared__ double sred[256];
    __shared__ int sicnt[256];

    const int b = blockIdx.x;
    const int t = threadIdx.x;
    const int w = t >> 6;
    const int lane = t & 63;

    // ---------------- bg blocks ----------------
    if (b >= PAIRB) {
        const int idx = b - PAIRB;          // 0..255
        const float4* in4 = (const float4*)in;
        const float4* tg4 = (const float4*)tg;
        float s = 0.0f;
        for (int e = idx * 256 + t; e < NV; e += BGB * 256) {   // 9 iters
            int n = e / HV;
            int r = e - n * HV;
            float4 x4 = in4[n * CV + r];
            float4 t4 = tg4[n * CV + r];
            const float* xp = &x4.x;
            const float* tp = &t4.x;
#pragma unroll
            for (int q = 0; q < 4; ++q) {
                float x = xp[q], tt = tp[q];
                float u = __expf(-fabsf(x));
                s += fmaxf(x, 0.0f) - x * tt + __logf(1.0f + u);
            }
        }
#pragma unroll
        for (int m = 32; m >= 1; m >>= 1) s += __shfl_xor(s, m);
        if (lane == 0) swf[w] = s;
        __syncthreads();
        if (t == 0) {
            bgpart[idx] = (double)(swf[0] + swf[1] + swf[2] + swf[3]);
            __hip_atomic_fetch_add(bgDone, 1, RL, SCOPE);   // own line
        }
        return;
    }

    // ---------------- pair blocks ----------------
    const bool diag = (b < NDIAG);
    int ti, tj;
    if (diag) {
        ti = b; tj = b;
    } else {
        int rem = b - NDIAG;                // 0..299 -> (ti<tj)
        ti = 0;
        while (rem >= (NTILE - 1) - ti) { rem -= (NTILE - 1) - ti; ++ti; }
        tj = ti + 1 + rem;
    }

    if (t < 8) {                            // px/py are plain inputs
        int g = (t < 4) ? (ti * TILE + t) : (tj * TILE + (t - 4));
        sPx[t] = px[g];
        sPy[t] = py[g];
    }

    if (diag) {
        // ---- gather group ti: 4 rows of P+G, term1, fingerprint ----
        for (int r = 0; r < TILE; ++r) {
            const int g = ti * TILE + r;
            const int base = py[g] * N_W + px[g];
            float s = 0.0f;
            unsigned long long h = 0ull;
            for (int k = t; k < NK; k += 256) {
                int n = k / N_C;
                int c = k - n * N_C;
                int off = n * CHW + c * HW + base;
                float p = in[off];
                float gg = tg[off];
                sPI[r * NK + k] = p;
                Pt[g * NK + k] = p;
                Gt[g * NK + k] = gg;
                s += (p > 0.0f) ? p * __logf(p) : 0.0f;
                unsigned long long m = (unsigned long long)__float_as_uint(gg)
                                     ^ (0x9E3779B97F4A7C15ULL * (unsigned long long)(k + 1));
                m *= 0xC2B2AE3D27D4EB4FULL;
                h ^= m ^ (m >> 31);
            }
#pragma unroll
            for (int m = 32; m >= 1; m >>= 1) {
                s += __shfl_xor(s, m);
                h ^= (unsigned long long)__shfl_xor((long long)h, m);
            }
            if (lane == 0) { swf[w] = s; swh[w] = h; }
            __syncthreads();
            if (t == 0) {
                float v = swf[0] + swf[1] + swf[2] + swf[3];
                unsigned long long hv = swh[0] ^ swh[1] ^ swh[2] ^ swh[3];
                term1[g] = v; fpr[g] = hv;
                sT1[r] = v; sT1[4 + r] = v;
                sFp[r] = hv; sFp[4 + r] = hv;
            }
            __syncthreads();
        }
        // publish: release covers Pt/Gt/term1/fpr stores (R11-proven pattern)
        if (t == 0)
            __hip_atomic_fetch_add(&rowDone[ti * 16], 1, RL, SCOPE);
    } else {
        // ---- gate on both groups: <=24 pollers/line, slow cadence ----
        if (t == 0) {
            while (!(__hip_atomic_load(&rowDone[ti * 16], RX, SCOPE) != 0 &&
                     __hip_atomic_load(&rowDone[tj * 16], RX, SCOPE) != 0))
                __builtin_amdgcn_s_sleep(16);
        }
        __syncthreads();
        __builtin_amdgcn_fence(AQ, "agent");    // one invalidate per block

        if (t < 8) {
            int g = (t < 4) ? (ti * TILE + t) : (tj * TILE + (t - 4));
            sT1[t] = term1[g];
            sFp[t] = fpr[g];
        }
        {   // stage 4 i-rows and 4 j-rows of P (float4 coalesced)
            const float4* Pt4 = (const float4*)Pt;
            float4* sI4 = (float4*)sPI;
            float4* sJ4 = (float4*)sPJ;
            for (int idx = t; idx < TILE * NK4; idx += 256) {
                int r = idx / NK4, q = idx - r * NK4;
                sI4[idx] = Pt4[(ti * TILE + r) * NK4 + q];
                sJ4[idx] = Pt4[(tj * TILE + r) * NK4 + q];
            }
        }
    }
    __syncthreads();

    // ---- pair compute (shared by diag/off-diag) ----
    const float* sJbase = diag ? sPI : sPJ;
    const float2* sPI2 = (const float2*)sPI;
    const int I = ti * TILE + w;
    float2 piv[7];
#pragma unroll
    for (int it = 0; it < 7; ++it) piv[it] = sPI2[w * NK2 + lane + it * 64];

    double kl = 0.0;
    int cnt = 0;
#pragma unroll
    for (int bb = 0; bb < TILE; ++bb) {
        const int J = tj * TILE + bb;
        const float2* pj2 = (const float2*)(sJbase + bb * NK);
        float cross = 0.0f;
#pragma unroll
        for (int it = 0; it < 7; ++it) {
            float2 pj = pj2[lane + it * 64];
            cross = fmaf(piv[it].x, pj.x, cross);
            cross = fmaf(piv[it].y, pj.y, cross);
        }
#pragma unroll
        for (int m = 32; m >= 1; m >>= 1) cross += __shfl_xor(cross, m);

        bool eqv;
        if (I == J) {
            eqv = true;                          // masked out anyway
        } else if (sFp[w] != sFp[4 + bb]) {
            eqv = false;                         // fp differ -> rows differ (exact)
        } else {
            // rare: fingerprints match, verify exactly from global Gt
            const float2* gi = (const float2*)(Gt + I * NK);
            const float2* gj = (const float2*)(Gt + J * NK);
            int ef = 1;
#pragma unroll
            for (int it = 0; it < 7; ++it) {
                int q = lane + it * 64;
                float2 a = gi[q], c2 = gj[q];
                ef &= (a.x == c2.x) & (a.y == c2.y);
            }
            eqv = __all(ef);
        }
        if (lane == 0) {
            float Dij = (sT1[4 + bb] - cross) * (1.0f / (float)N_N);
            float Dji = (sT1[w] - cross) * (1.0f / (float)N_N);
            float L = eqv ? (Dij + Dji)
                          : (float)(N_N * N_C) *
                            (fmaxf(SIGMA_F - Dij, 0.0f) + fmaxf(SIGMA_F - Dji, 0.0f));
            // count each unordered pair once (I<J); halved sum/cnt keeps ratio
            bool mask = (I < J) && (sPx[w] != sPx[4 + bb]) && (sPy[w] != sPy[4 + bb]);
            if (mask) { kl += (double)L; cnt += 1; }
        }
    }

    if (lane == 0) { skl[w] = kl; scnt4[w] = cnt; }
    __syncthreads();
    if (t == 0) {
        klpart[b] = skl[0] + skl[1] + skl[2] + skl[3];
        cntpart[b] = scnt4[0] + scnt4[1] + scnt4[2] + scnt4[3];
        int old = __hip_atomic_fetch_add(pairDone, 1, RL, SCOPE);
        slast = (old == PAIRB - 1) ? 1 : 0;
    }
    __syncthreads();

    // ---- finalization by the last pair block ----
    if (slast) {
        if (t == 0) {        // single poller, benign
            while (__hip_atomic_load(bgDone, RX, SCOPE) < BGB)
                __builtin_amdgcn_s_sleep(8);
        }
        __syncthreads();
        __builtin_amdgcn_fence(AQ, "agent");
        double s = 0.0;
        for (int q = t; q < BGB; q += 256) s += bgpart[q];
        double kq = 0.0;
        int cq = 0;
        for (int q = t; q < PAIRB; q += 256) { kq += klpart[q]; cq += cntpart[q]; }
        sred[t] = s;
        __syncthreads();
        for (int off = 128; off > 0; off >>= 1) {
            if (t < off) sred[t] += sred[t + off];
            __syncthreads();
        }
        double bg_sum = sred[0];
        __syncthreads();
        sred[t] = kq;
        sicnt[t] = cq;
        __syncthreads();
        for (int off = 128; off > 0; off >>= 1) {
            if (t < off) { sred[t] += sred[t + off]; sicnt[t] += sicnt[t + off]; }
            __syncthreads();
        }
        if (t == 0)
            out[0] = (float)(bg_sum / (double)NHW + sred[0] / (double)sicnt[0]);
    }
}

// ---------------- launch ---------------------------------------------------
extern "C" void kernel_launch(void* const* d_in, const int* in_sizes, int n_in,
                              void* d_out, int out_size, void* d_ws, size_t ws_size,
                              hipStream_t stream) {
    const float* inputs  = (const float*)d_in[0];
    const float* targets = (const float*)d_in[1];
    const int*   px      = (const int*)d_in[2];
    const int*   py      = (const int*)d_in[3];
    float* out = (float*)d_out;

    char* ws = (char*)d_ws;
    int*    rowDone  = (int*)ws;                          // 25 x 64B lines
    int*    bgDone   = (int*)(ws + 1664);                 // own line
    int*    pairDone = (int*)(ws + 1792);                 // own line
    double* bgpart   = (double*)(ws + 2048);              // 256*8 = 2048
    double* klpart   = (double*)(ws + 4096);              // 325*8 = 2600
    int*    cntpart  = (int*)(ws + 6784);                 // 325*4 = 1300
    float*  term1    = (float*)(ws + 8192);               // 100*4
    unsigned long long* fpr = (unsigned long long*)(ws + 8704);  // 100*8
    float*  Pt       = (float*)(ws + 9728);               // 358400
    float*  Gt       = (float*)(ws + 368128);             // 358400

    hipMemsetAsync(ws, 0, 2048, stream);                  // zero gates/counters
    mono_kernel<<<GRID, 256, 0, stream>>>(
        inputs, targets, px, py, rowDone, bgDone, pairDone,
        bgpart, klpart, cntpart, term1, fpr, Pt, Gt, out);
}

// Round 14
// 25.250 us; speedup vs baseline: 7.2810x; 2.0237x over previous
//
#include <hip/hip_runtime.h>
#include <hip/hip_bf16.h>

#define N_N 128
#define N_C 7
#define N_H 96
#define N_W 192
#define HW (N_H * N_W)            // 18432
#define CHW (N_C * HW)            // 129024
#define NHW (N_N * HW)            // 2359296
#define NPTS 100
#define NK (N_N * N_C)            // 896
#define NK2 (NK / 2)              // 448 float2 per row
#define NK4 (NK / 4)              // 224 float4 per row
#define NV (NHW / 4)              // 589824 float4 per tensor (channel 0)
#define HV (HW / 4)               // 4608
#define CV (CHW / 4)              // 32256
#define SIGMA_F 2.0f

#define BG_BLOCKS 1024
#define TILE 4
#define NTILE (NPTS / TILE)       // 25
#define PAIRT (NTILE * (NTILE + 1) / 2)   // 325 tiles with ti<=tj

#define RL __ATOMIC_RELEASE
#define SCOPE __HIP_MEMORY_SCOPE_AGENT

// ---------------- kernel 1 --------------------------------------------------
// blocks [0,1024)    : BCE-with-logits partial sums over channel 0 (fast math)
// blocks [1024,1124) : gather P row i (transposed) + term1[i]
// blocks [1124,1224) : G row i -> fingerprint[i] only (no Gt store)
// block  1224        : zero doneCnt for K2
__global__ __launch_bounds__(256) void fusedA_kernel(
        const float* __restrict__ in, const float* __restrict__ tg,
        const int* __restrict__ px, const int* __restrict__ py,
        double* __restrict__ bgpart,        // [1024]
        float* __restrict__ Pt,             // [100][896]
        float* __restrict__ term1,          // [100]
        unsigned long long* __restrict__ fpr,  // [100]
        int* __restrict__ doneCnt) {
    __shared__ float swf[4];
    __shared__ unsigned long long swh[4];
    const int b = blockIdx.x;
    const int t = threadIdx.x;
    const int w = t >> 6;
    const int lane = t & 63;

    if (b >= BG_BLOCKS + 2 * NPTS) {
        if (t == 0) *doneCnt = 0;
        return;
    }

    if (b < BG_BLOCKS) {
        // ---- bg sweep, fast transcendental path ----
        const float4* in4 = (const float4*)in;
        const float4* tg4 = (const float4*)tg;
        float s = 0.0f;
        for (int e = b * 256 + t; e < NV; e += BG_BLOCKS * 256) {
            int n = e / HV;
            int r = e - n * HV;
            float4 x4 = in4[n * CV + r];
            float4 t4 = tg4[n * CV + r];
            const float* xp = &x4.x;
            const float* tp = &t4.x;
#pragma unroll
            for (int q = 0; q < 4; ++q) {
                float x = xp[q], tt = tp[q];
                float u = __expf(-fabsf(x));
                s += fmaxf(x, 0.0f) - x * tt + __logf(1.0f + u);
            }
        }
#pragma unroll
        for (int m = 32; m >= 1; m >>= 1) s += __shfl_xor(s, m);
        if (lane == 0) swf[w] = s;
        __syncthreads();
        if (t == 0) bgpart[b] = (double)(swf[0] + swf[1] + swf[2] + swf[3]);
    } else if (b < BG_BLOCKS + NPTS) {
        // ---- gather P row i + term1 ----
        const int i = b - BG_BLOCKS;
        const int base = py[i] * N_W + px[i];
        float s = 0.0f;
        for (int k = t; k < NK; k += 256) {
            int n = k / N_C;
            int c = k - n * N_C;
            float p = in[n * CHW + c * HW + base];
            Pt[i * NK + k] = p;
            s += (p > 0.0f) ? p * __logf(p) : 0.0f;
        }
#pragma unroll
        for (int m = 32; m >= 1; m >>= 1) s += __shfl_xor(s, m);
        if (lane == 0) swf[w] = s;
        __syncthreads();
        if (t == 0) term1[i] = swf[0] + swf[1] + swf[2] + swf[3];
    } else {
        // ---- G row i -> fingerprint only ----
        const int i = b - BG_BLOCKS - NPTS;
        const int base = py[i] * N_W + px[i];
        unsigned long long h = 0ull;
        for (int k = t; k < NK; k += 256) {
            int n = k / N_C;
            int c = k - n * N_C;
            float g = tg[n * CHW + c * HW + base];
            unsigned long long m = (unsigned long long)__float_as_uint(g)
                                 ^ (0x9E3779B97F4A7C15ULL * (unsigned long long)(k + 1));
            m *= 0xC2B2AE3D27D4EB4FULL;
            h ^= m ^ (m >> 31);
        }
#pragma unroll
        for (int m = 32; m >= 1; m >>= 1)
            h ^= (unsigned long long)__shfl_xor((long long)h, m);
        if (lane == 0) swh[w] = h;
        __syncthreads();
        if (t == 0) fpr[i] = swh[0] ^ swh[1] ^ swh[2] ^ swh[3];
    }
}

// ---------------- kernel 2: upper-triangle pairs + finalization -------------
// 325 blocks: tile (ti,tj), ti<=tj. Wave w owns i-row w (registers); the 4
// j-rows are staged in LDS (shared by all 4 waves). Fingerprint-only eq.
// Last-done block finalizes.
__global__ __launch_bounds__(256) void pairsfin_kernel(
        const float* __restrict__ Pt,
        const float* __restrict__ term1,
        const int* __restrict__ px, const int* __restrict__ py,
        const unsigned long long* __restrict__ fpr,
        const double* __restrict__ bgpart,   // [1024]
        double* __restrict__ klpart,         // [325]
        int* __restrict__ cntpart,           // [325]
        int* __restrict__ doneCnt,           // [1], zeroed by K1
        float* __restrict__ out) {
    __shared__ __align__(16) float sPJ[TILE * NK];   // 14336 B (j-rows only)
    __shared__ float sT1[8];
    __shared__ unsigned long long sFp[8];
    __shared__ int sPx[8], sPy[8];
    __shared__ double skl[4];
    __shared__ int scnt4[4];
    __shared__ int slast;
    __shared__ double sred[256];
    __shared__ int sicnt[256];

    const int bidx = blockIdx.x;
    const int t = threadIdx.x;
    const int w = t >> 6;
    const int lane = t & 63;

    // decode bidx -> (ti, tj) with ti <= tj
    int ti = 0, rem = bidx;
    while (rem >= NTILE - ti) { rem -= NTILE - ti; ++ti; }
    const int tj = ti + rem;

    if (t < 8) {
        int g = (t < 4) ? (ti * TILE + t) : (tj * TILE + (t - 4));
        sT1[t] = term1[g];
        sFp[t] = fpr[g];
        sPx[t] = px[g];
        sPy[t] = py[g];
    }
    {   // stage 4 j-rows of P (float4 coalesced, 3.5/thread)
        const float4* Pt4 = (const float4*)Pt;
        float4* sJ4 = (float4*)sPJ;
        for (int idx = t; idx < TILE * NK4; idx += 256) {
            int r = idx / NK4, q = idx - r * NK4;
            sJ4[idx] = Pt4[(tj * TILE + r) * NK4 + q];
        }
    }

    // i-row fragment straight from global Pt into registers (coalesced, L2)
    const int I = ti * TILE + w;
    const float2* PtI2 = (const float2*)(Pt + (size_t)I * NK);
    float2 piv[7];
#pragma unroll
    for (int it = 0; it < 7; ++it) piv[it] = PtI2[lane + it * 64];

    __syncthreads();

    double kl = 0.0;
    int cnt = 0;
#pragma unroll
    for (int bb = 0; bb < TILE; ++bb) {
        const int J = tj * TILE + bb;
        const float2* pj2 = (const float2*)(sPJ + bb * NK);
        float cross = 0.0f;
#pragma unroll
        for (int it = 0; it < 7; ++it) {
            float2 pj = pj2[lane + it * 64];
            cross = fmaf(piv[it].x, pj.x, cross);
            cross = fmaf(piv[it].y, pj.y, cross);
        }
#pragma unroll
        for (int m = 32; m >= 1; m >>= 1) cross += __shfl_xor(cross, m);

        // eq via 64-bit row fingerprints (exact for distinct hashes; equal
        // rows hash equal; false-equal collision prob ~2^-64 per pair)
        bool eqv = (I == J) || (sFp[w] == sFp[4 + bb]);
        if (lane == 0) {
            float Dij = (sT1[4 + bb] - cross) * (1.0f / (float)N_N);
            float Dji = (sT1[w] - cross) * (1.0f / (float)N_N);
            float L = eqv ? (Dij + Dji)
                          : (float)(N_N * N_C) *
                            (fmaxf(SIGMA_F - Dij, 0.0f) + fmaxf(SIGMA_F - Dji, 0.0f));
            // count each unordered pair once (I<J); halved sum/cnt keeps ratio
            bool mask = (I < J) && (sPx[w] != sPx[4 + bb]) && (sPy[w] != sPy[4 + bb]);
            if (mask) { kl += (double)L; cnt += 1; }
        }
    }

    if (lane == 0) { skl[w] = kl; scnt4[w] = cnt; }
    __syncthreads();
    if (t == 0) {
        klpart[bidx] = skl[0] + skl[1] + skl[2] + skl[3];
        cntpart[bidx] = scnt4[0] + scnt4[1] + scnt4[2] + scnt4[3];
        // release: prior stores visible to whoever observes the increment
        int old = __hip_atomic_fetch_add(doneCnt, 1, RL, SCOPE);
        slast = (old == PAIRT - 1) ? 1 : 0;
    }
    __syncthreads();

    if (slast) {
        __builtin_amdgcn_fence(__ATOMIC_ACQUIRE, "agent");   // one invalidate
        double s = 0.0;
        for (int q = t; q < BG_BLOCKS; q += 256) s += bgpart[q];
        double kq = 0.0;
        int cq = 0;
        for (int q = t; q < PAIRT; q += 256) { kq += klpart[q]; cq += cntpart[q]; }
        sred[t] = s;
        __syncthreads();
        for (int off = 128; off > 0; off >>= 1) {
            if (t < off) sred[t] += sred[t + off];
            __syncthreads();
        }
        double bg_sum = sred[0];
        __syncthreads();
        sred[t] = kq;
        sicnt[t] = cq;
        __syncthreads();
        for (int off = 128; off > 0; off >>= 1) {
            if (t < off) { sred[t] += sred[t + off]; sicnt[t] += sicnt[t + off]; }
            __syncthreads();
        }
        if (t == 0)
            out[0] = (float)(bg_sum / (double)NHW + sred[0] / (double)sicnt[0]);
    }
}

// ---------------- launch ---------------------------------------------------
extern "C" void kernel_launch(void* const* d_in, const int* in_sizes, int n_in,
                              void* d_out, int out_size, void* d_ws, size_t ws_size,
                              hipStream_t stream) {
    const float* inputs  = (const float*)d_in[0];
    const float* targets = (const float*)d_in[1];
    const int*   px      = (const int*)d_in[2];
    const int*   py      = (const int*)d_in[3];
    float* out = (float*)d_out;

    char* ws = (char*)d_ws;
    int*    doneCnt = (int*)ws;                           // 128 B reserved
    double* bgpart  = (double*)(ws + 256);                // 1024*8 = 8192
    double* klpart  = (double*)(ws + 8448);               // 325*8 = 2600
    int*    cntpart = (int*)(ws + 11264);                 // 325*4 = 1300
    float*  term1   = (float*)(ws + 12800);               // 100*4
    unsigned long long* fpr = (unsigned long long*)(ws + 13312);  // 100*8
    float*  Pt      = (float*)(ws + 14336);               // 358400

    fusedA_kernel<<<BG_BLOCKS + 2 * NPTS + 1, 256, 0, stream>>>(
        inputs, targets, px, py, bgpart, Pt, term1, fpr, doneCnt);
    pairsfin_kernel<<<PAIRT, 256, 0, stream>>>(
        Pt, term1, px, py, fpr, bgpart, klpart, cntpart, doneCnt, out);
}